// Round 1
// 268.060 us; speedup vs baseline: 1.1961x; 1.1961x over previous
//
#include <hip/hip_runtime.h>

// Problem constants
#define RB   16      // batch
#define RR   37      // OUT_R
#define RC   12      // OUT_C
#define CH   128     // channels
#define WN   60      // WIN = 5*OUT_C
#define P1R  41      // padded rows input_1 (2+37+2)
#define P2R  45      // padded rows input_2 (4+37+4)
#define PCOL 16      // padded cols (2+12+2)
#define NROWS2 41    // number of B row-start indices (r+d in 0..40)

#define N1 (RB*P1R*PCOL*CH)   // 1,343,488
#define N2 (RB*P2R*PCOL*CH)   // 1,474,560
#define NS (RB*NROWS2*RC*CH)  // 1,007,616  (B-stats entries)

// ---------------------------------------------------------------------------
// Kernel 1: zero-padded copies of both inputs.
// ---------------------------------------------------------------------------
__global__ void pad_kernel(const float* __restrict__ in1,
                           const float* __restrict__ in2,
                           float* __restrict__ p1,
                           float* __restrict__ p2) {
    int idx = blockIdx.x * 256 + threadIdx.x;
    if (idx < N1) {
        int c   = idx & 127;
        int col = (idx >> 7) & 15;
        int rb  = idx >> 11;
        int row = rb % P1R;
        int b   = rb / P1R;
        int ir = row - 2, ic = col - 2;
        float v = 0.f;
        if ((unsigned)ir < (unsigned)RR && (unsigned)ic < (unsigned)RC)
            v = in1[(((size_t)b*RR + ir)*RC + ic)*CH + c];
        p1[idx] = v;
    } else if (idx < N1 + N2) {
        int j   = idx - N1;
        int c   = j & 127;
        int col = (j >> 7) & 15;
        int rb  = j >> 11;
        int row = rb % P2R;
        int b   = rb / P2R;
        int ir = row - 4, ic = col - 2;
        float v = 0.f;
        if ((unsigned)ir < (unsigned)RR && (unsigned)ic < (unsigned)RC)
            v = in2[(((size_t)b*RR + ir)*RC + ic)*CH + c];
        p2[j] = v;
    }
}

// ---------------------------------------------------------------------------
// Kernel 2: B-patch statistics.  For window-row index i (= r+d, 0..40) the
// patch starts at physical pad2 row s = (i<=38 ? i : i-2), spans 5 rows;
// for each j2, cols j2..j2+4.  Writes muB/isB [b][i][j2][c].
// ---------------------------------------------------------------------------
__global__ __launch_bounds__(128)
void stats_kernel(const float* __restrict__ p2,
                  float* __restrict__ muB,
                  float* __restrict__ isB) {
    const int i = blockIdx.x;       // 0..40
    const int b = blockIdx.y;       // 0..15
    const int c = threadIdx.x;      // 0..127
    const int s = (i <= 38) ? i : i - 2;

    const float* base = p2 + ((size_t)(b*P2R + s)*PCOL)*CH + c;
    float CS[16], CQ[16];
    #pragma unroll
    for (int q = 0; q < 16; ++q) { CS[q] = 0.f; CQ[q] = 0.f; }
    #pragma unroll
    for (int ki = 0; ki < 5; ++ki) {
        #pragma unroll
        for (int q = 0; q < 16; ++q) {
            float v = base[(ki*PCOL + q)*CH];
            CS[q] += v;
            CQ[q] = fmaf(v, v, CQ[q]);
        }
    }
    const size_t ob = ((size_t)(b*NROWS2 + i)*RC)*CH + c;
    #pragma unroll
    for (int j2 = 0; j2 < 12; ++j2) {
        float s5 = 0.f, q5 = 0.f;
        #pragma unroll
        for (int k = 0; k < 5; ++k) { s5 += CS[j2+k]; q5 += CQ[j2+k]; }
        float mu = s5 * 0.04f;
        float var = fmaf(-mu, mu, q5 * 0.04f);
        muB[ob + (size_t)j2*CH] = mu;
        isB[ob + (size_t)j2*CH] = rsqrtf(var);
    }
}

// ---------------------------------------------------------------------------
// Accumulation core: stream 9 B rows (pad2 rows r..r+8), fully static
// (d,ki) pairing via template offset table.  offs[d] = sd(d) - r.
// ---------------------------------------------------------------------------
template<int O0, int O1, int O2, int O3, int O4>
__device__ __forceinline__ void corr_core(const float* __restrict__ Bb,
                                          const float (&As)[5][5],
                                          float (&acc)[60]) {
    const int offs[5] = {O0, O1, O2, O3, O4};
    #pragma unroll
    for (int t = 0; t < 9; ++t) {
        float brow[16];
        #pragma unroll
        for (int q = 0; q < 16; ++q)
            brow[q] = Bb[((size_t)(t*PCOL + q))*CH];
        #pragma unroll
        for (int d = 0; d < 5; ++d) {
            const int ki = t - offs[d];   // compile-time after unroll
            if (ki >= 0 && ki < 5) {
                #pragma unroll
                for (int kj = 0; kj < 5; ++kj) {
                    const float a = As[ki][kj];
                    #pragma unroll
                    for (int j2 = 0; j2 < 12; ++j2)
                        acc[d*12 + j2] = fmaf(a, brow[kj + j2], acc[d*12 + j2]);
                }
            }
        }
    }
}

// ---------------------------------------------------------------------------
// Kernel 3: main correlation.  Block (jg,r,b); thread (c, jo) -> j=jg*2+jo.
// Each thread computes ALL 60 window outputs for (b,r,j,c).
// Epilogue: stage each j-half (128 threads x 60 floats = 30720 B) into LDS,
// then ALL 256 threads write the fully-contiguous 30720-B output region as
// consecutive float4s -> per-instruction coalesced (16 B/lane, 1 KiB/wave).
// (Old version stored per-thread 240-B runs: 64 distinct lines touched per
// store instruction, partial-line writes -> store-backpressure bound.)
// ---------------------------------------------------------------------------
__global__ __launch_bounds__(256, 3)
void corr2_kernel(const float* __restrict__ p1,
                  const float* __restrict__ p2,
                  const float* __restrict__ muB,
                  const float* __restrict__ isB,
                  float* __restrict__ out) {
    const int jg = blockIdx.x;   // 0..5
    const int r  = blockIdx.y;   // 0..36
    const int b  = blockIdx.z;   // 0..15
    const int t  = threadIdx.x;
    const int c  = t & 127;
    const int jo = t >> 7;
    const int j  = jg*2 + jo;

    // ---- A strip 5x5 (pad1 rows r..r+4, cols j..j+4), in registers
    const float* Ab = p1 + ((size_t)(b*P1R + r)*PCOL + j)*CH + c;
    float As[5][5];
    #pragma unroll
    for (int ki = 0; ki < 5; ++ki)
        #pragma unroll
        for (int kj = 0; kj < 5; ++kj)
            As[ki][kj] = Ab[(ki*PCOL + kj)*CH];

    // ---- A stats (inline)
    float sa = 0.f, qa = 0.f;
    #pragma unroll
    for (int ki = 0; ki < 5; ++ki)
        #pragma unroll
        for (int kj = 0; kj < 5; ++kj) {
            float v = As[ki][kj];
            sa += v;
            qa = fmaf(v, v, qa);
        }
    const float mu_a = sa * 0.04f;
    const float isa_ = rsqrtf(fmaf(-mu_a, mu_a, qa * 0.04f));

    // ---- 60 accumulators
    float acc[60];
    #pragma unroll
    for (int k = 0; k < 60; ++k) acc[k] = 0.f;

    const float* Bb = p2 + ((size_t)(b*P2R + r)*PCOL)*CH + c;
    // offs[d] = row_starts2[r+d] - r;  row_starts2[i] = i (i<=38), 37, 38
    if (r <= 34)      corr_core<0,1,2,3,4>(Bb, As, acc);
    else if (r == 35) corr_core<0,1,2,3,2>(Bb, As, acc);
    else              corr_core<0,1,2,1,2>(Bb, As, acc);

    // ---- Epilogue part 1: apply stats in-register
    const float nma = -25.f * mu_a;
    const float* mb = muB + ((size_t)(b*NROWS2 + r)*RC)*CH + c;
    const float* ib = isB + ((size_t)(b*NROWS2 + r)*RC)*CH + c;
    #pragma unroll
    for (int d = 0; d < 5; ++d) {
        #pragma unroll
        for (int j2 = 0; j2 < 12; ++j2) {
            float m  = mb[((size_t)(d*RC + j2))*CH];
            float iv = ib[((size_t)(d*RC + j2))*CH];
            acc[d*12 + j2] = fmaf(nma, m, acc[d*12 + j2]) * (isa_ * iv);
        }
    }

    // ---- Epilogue part 2: LDS-staged coalesced store.
    // Region for this block = out[(b,r,jg*2) .. (b,r,jg*2+1)] : 2 x 7680
    // contiguous floats.  Two passes (one per j-half), 30720 B LDS reused.
    __shared__ float4 lds4[1920];   // 30720 B  (keeps 3 blocks/CU; VGPR-limited)
    float* obase = out + ((size_t)((b*RR + r)*RC + jg*2))*(CH*WN);

    #pragma unroll
    for (int pass = 0; pass < 2; ++pass) {
        if (pass) __syncthreads();          // store readers done before restage
        if (jo == pass) {
            #pragma unroll
            for (int w4 = 0; w4 < 15; ++w4)
                lds4[c*15 + w4] = make_float4(acc[w4*4+0], acc[w4*4+1],
                                              acc[w4*4+2], acc[w4*4+3]);
        }
        __syncthreads();
        float4* o4 = reinterpret_cast<float4*>(obase + (size_t)pass*(CH*WN));
        #pragma unroll
        for (int i = 0; i < 8; ++i) {
            int g4 = i*256 + t;             // 1920 float4 = 30720 B region
            if (g4 < 1920)                  // i==7: only waves 0-1 store
                o4[g4] = lds4[g4];
        }
    }
}

// ---------------------------------------------------------------------------
// Fallback (ws too small): round-1 predicated kernel, d split across blocks.
// ---------------------------------------------------------------------------
__global__ __launch_bounds__(256, 2)
void corr_fallback(const float* __restrict__ A,
                   const float* __restrict__ Bp,
                   float* __restrict__ out) {
    const int d  = blockIdx.x;
    const int r  = blockIdx.y;
    const int b  = blockIdx.z;
    const int t  = threadIdx.x;
    const int c  = t & 127;
    const int jh = t >> 7;
    const int jbase = jh * 6;

    const int rd = r + d;
    const int sd = (rd <= 38) ? rd : rd - 2;

    float As[5][10];
    #pragma unroll
    for (int ki = 0; ki < 5; ++ki) {
        int ir = r + ki - 2;
        bool rok = (unsigned)ir < (unsigned)RR;
        #pragma unroll
        for (int q = 0; q < 10; ++q) {
            int ic = jbase + q - 2;
            bool ok = rok && ((unsigned)ic < (unsigned)RC);
            As[ki][q] = ok ? A[(((size_t)b*RR + ir)*RC + ic)*CH + c] : 0.f;
        }
    }

    float mu_a[6], isa[6];
    {
        float CS[10], CQ[10];
        #pragma unroll
        for (int q = 0; q < 10; ++q) {
            float s = 0.f, ss = 0.f;
            #pragma unroll
            for (int ki = 0; ki < 5; ++ki) { float v = As[ki][q]; s += v; ss = fmaf(v,v,ss); }
            CS[q] = s; CQ[q] = ss;
        }
        #pragma unroll
        for (int jj = 0; jj < 6; ++jj) {
            float s = 0.f, q2 = 0.f;
            #pragma unroll
            for (int k = 0; k < 5; ++k) { s += CS[jj+k]; q2 += CQ[jj+k]; }
            float m = s * 0.04f;
            mu_a[jj] = m;
            isa[jj] = rsqrtf(fmaf(-m, m, q2 * 0.04f));
        }
    }

    float acc[6][12];
    #pragma unroll
    for (int jj = 0; jj < 6; ++jj)
        #pragma unroll
        for (int j2 = 0; j2 < 12; ++j2) acc[jj][j2] = 0.f;

    float CSb[16], CQb[16];
    #pragma unroll
    for (int q = 0; q < 16; ++q) { CSb[q] = 0.f; CQb[q] = 0.f; }

    #pragma unroll
    for (int ki = 0; ki < 5; ++ki) {
        float brow[16];
        int ir = sd + ki - 4;
        bool rok = (unsigned)ir < (unsigned)RR;
        #pragma unroll
        for (int q = 0; q < 16; ++q) {
            int ic = q - 2;
            bool ok = rok && ((unsigned)ic < (unsigned)RC);
            brow[q] = ok ? Bp[(((size_t)b*RR + ir)*RC + ic)*CH + c] : 0.f;
        }
        #pragma unroll
        for (int q = 0; q < 16; ++q) {
            CSb[q] += brow[q];
            CQb[q] = fmaf(brow[q], brow[q], CQb[q]);
        }
        #pragma unroll
        for (int jj = 0; jj < 6; ++jj)
            #pragma unroll
            for (int kj = 0; kj < 5; ++kj) {
                float a = As[ki][jj + kj];
                #pragma unroll
                for (int j2 = 0; j2 < 12; ++j2)
                    acc[jj][j2] = fmaf(a, brow[kj + j2], acc[jj][j2]);
            }
    }

    float mu_b[12], isb[12];
    #pragma unroll
    for (int j2 = 0; j2 < 12; ++j2) {
        float s = 0.f, q2 = 0.f;
        #pragma unroll
        for (int k = 0; k < 5; ++k) { s += CSb[j2+k]; q2 += CQb[j2+k]; }
        float m = s * 0.04f;
        mu_b[j2] = m;
        isb[j2] = rsqrtf(fmaf(-m, m, q2 * 0.04f));
    }

    float* ob = out + ((size_t)((b*RR + r)*RC + jbase)) * (CH*WN) + (size_t)c*WN + d*12;
    #pragma unroll
    for (int jj = 0; jj < 6; ++jj) {
        float o[12];
        float ma25 = 25.f * mu_a[jj];
        #pragma unroll
        for (int j2 = 0; j2 < 12; ++j2) {
            float val = fmaf(-ma25, mu_b[j2], acc[jj][j2]);
            o[j2] = val * (isa[jj] * isb[j2]);
        }
        float4* row4 = reinterpret_cast<float4*>(ob + (size_t)jj * (CH*WN));
        row4[0] = make_float4(o[0], o[1], o[2],  o[3]);
        row4[1] = make_float4(o[4], o[5], o[6],  o[7]);
        row4[2] = make_float4(o[8], o[9], o[10], o[11]);
    }
}

// ---------------------------------------------------------------------------
extern "C" void kernel_launch(void* const* d_in, const int* in_sizes, int n_in,
                              void* d_out, int out_size, void* d_ws, size_t ws_size,
                              hipStream_t stream) {
    const float* in1 = (const float*)d_in[0];
    const float* in2 = (const float*)d_in[1];
    float* out = (float*)d_out;

    const size_t need = (size_t)(N1 + N2 + 2*NS) * sizeof(float);

    if (ws_size >= need) {
        float* p1  = (float*)d_ws;
        float* p2  = p1 + N1;
        float* muB = p2 + N2;
        float* isB = muB + NS;

        const int total = N1 + N2;
        pad_kernel<<<(total + 255) / 256, 256, 0, stream>>>(in1, in2, p1, p2);
        stats_kernel<<<dim3(NROWS2, RB), 128, 0, stream>>>(p2, muB, isB);
        corr2_kernel<<<dim3(6, RR, RB), 256, 0, stream>>>(p1, p2, muB, isB, out);
    } else {
        corr_fallback<<<dim3(5, RR, RB), 256, 0, stream>>>(in1, in2, out);
    }
}